// Round 3
// baseline (215.775 us; speedup 1.0000x reference)
//
#include <hip/hip_runtime.h>

// OHEM loss: exact k-th order statistic via radix select on a monotonic key,
// fused log-softmax NLL, masked mean.
//
// 6 launches:
//   init    : zero Ctrl
//   row     : read pred (256MB, nontemporal) 1 thread/row -> keys, nll,
//             hist[3] (top byte), pos_num
//   hist2/1 : redundant select-chain (LDS scan of completed hists) + filtered
//             histogram of the next byte
//   reduceF : select-chain to byte-1 level; definite rows -> reg sum/cnt;
//             equal-top24 rows (rare) -> 256 global buckets (hist0 fused)
//   final   : select byte 0 from buckets, combine, divide

typedef float f4 __attribute__((ext_vector_type(4)));

struct Ctrl {
    unsigned hist[4][256];   // hist[3..1] used
    unsigned pos_num;
    unsigned cnt;
    unsigned bcnt[256];      // byte-0 counts within selected 24-bit prefix
    float    bsum[256];      // nll sums per byte-0 bucket
    double   sum;
};

__global__ void init_kernel(unsigned* c, int words) {
    for (int i = threadIdx.x + blockIdx.x * blockDim.x; i < words;
         i += blockDim.x * gridDim.x)
        c[i] = 0u;
}

// Wave-aggregated LDS histogram add (top byte has few distinct values).
__device__ inline void wave_hist_add(unsigned* h, unsigned bucket) {
    unsigned long long todo = __ballot(1);
    while (todo) {
        int leader = (int)__builtin_ctzll(todo);
        unsigned b = __shfl(bucket, leader);
        unsigned long long same = __ballot(bucket == b) & todo;
        if ((int)(threadIdx.x & 63) == leader)
            atomicAdd(&h[b], (unsigned)__popcll(same));
        todo &= ~same;
    }
}

__global__ void __launch_bounds__(256)
row_kernel(const f4* __restrict__ pred4, const int* __restrict__ label,
           unsigned* __restrict__ keys, float* __restrict__ nll,
           Ctrl* __restrict__ c, int n) {
    __shared__ unsigned h[256];
    for (int i = threadIdx.x; i < 256; i += 256) h[i] = 0u;
    __syncthreads();

    int pos_local = 0;
    const int stride = gridDim.x * blockDim.x;
    for (int row = blockIdx.x * blockDim.x + threadIdx.x; row < n; row += stride) {
        const f4* p = pred4 + (size_t)row * 8;
        float r[32];
#pragma unroll
        for (int j = 0; j < 8; ++j) {
            f4 v = __builtin_nontemporal_load(&p[j]);
            r[4 * j + 0] = v.x; r[4 * j + 1] = v.y;
            r[4 * j + 2] = v.z; r[4 * j + 3] = v.w;
        }
        float m_nb = r[1];
#pragma unroll
        for (int j = 2; j < 32; ++j) m_nb = fmaxf(m_nb, r[j]);
        float m_all = fmaxf(m_nb, r[0]);

        float s = 0.f;
#pragma unroll
        for (int j = 0; j < 32; ++j) s += __expf(r[j] - m_all);

        int lab = label[row];
        int sl = lab; sl = sl < 0 ? 0 : sl; sl = sl > 31 ? 31 : sl;
        float xl = r[0];
#pragma unroll
        for (int j = 1; j < 32; ++j) xl = (j == sl) ? r[j] : xl;

        nll[row] = (m_all + __logf(s)) - xl;

        bool is_pos = (lab != 0);
        pos_local += is_pos ? 1 : 0;

        float ns = is_pos ? -__builtin_inff() : m_nb;
        unsigned u    = __float_as_uint(ns);
        unsigned ukey = (u & 0x80000000u) ? ~u : (u | 0x80000000u);
        unsigned dkey = ~ukey;                 // ascending dkey = descending float
        keys[row] = dkey;
        wave_hist_add(h, dkey >> 24);
    }

#pragma unroll
    for (int off = 32; off > 0; off >>= 1) pos_local += __shfl_down(pos_local, off);
    __shared__ int wsum[4];
    int wid = threadIdx.x >> 6;
    if ((threadIdx.x & 63) == 0) wsum[wid] = pos_local;
    __syncthreads();
    if (threadIdx.x == 0)
        atomicAdd(&c->pos_num, (unsigned)(wsum[0] + wsum[1] + wsum[2] + wsum[3]));

    for (int i = threadIdx.x; i < 256; i += 256)
        if (h[i]) atomicAdd(&c->hist[3][i], h[i]);
}

// Block-redundant radix select over completed histograms 3..upto_pass.
// Requires blockDim.x == 256.
__device__ void select_chain(const Ctrl* __restrict__ c, int n, int factor,
                             int upto_pass, unsigned& prefix_out,
                             unsigned& rank_out, bool& use_thr_out) {
    __shared__ unsigned s[256];
    __shared__ unsigned sh_byte, sh_rank;
    const int t = threadIdx.x;

    long long pos     = (long long)c->pos_num;
    long long neg_sum = pos * (long long)factor;
    long long num_neg = (long long)n - pos;
    long long idx     = neg_sum - 1;
    if (idx < 0) idx = 0;
    if (idx > (long long)n - 1) idx = (long long)n - 1;
    unsigned rank   = (unsigned)idx;
    unsigned prefix = 0u;

    for (int p = 3; p >= upto_pass; --p) {
        unsigned cnt = c->hist[p][t];
        __syncthreads();
        s[t] = cnt;
        __syncthreads();
#pragma unroll
        for (int off = 1; off < 256; off <<= 1) {
            unsigned v = (t >= off) ? s[t - off] : 0u;
            __syncthreads();
            s[t] += v;
            __syncthreads();
        }
        unsigned incl = s[t], excl = incl - cnt;
        if (cnt > 0u && excl <= rank && rank < incl) {
            sh_byte = (unsigned)t;
            sh_rank = rank - excl;
        }
        __syncthreads();
        prefix |= sh_byte << (8 * p);
        rank = sh_rank;
        __syncthreads();
    }
    prefix_out  = prefix;
    rank_out    = rank;
    use_thr_out = (num_neg > neg_sum);
}

__global__ void __launch_bounds__(256)
hist_kernel(const unsigned* __restrict__ keys, Ctrl* __restrict__ c,
            const int* __restrict__ factor_p, int n, int pass) {
    unsigned prefix, rank; bool use_thr;
    select_chain(c, n, factor_p[0], pass + 1, prefix, rank, use_thr);

    __shared__ unsigned h[256];
    for (int i = threadIdx.x; i < 256; i += 256) h[i] = 0u;
    __syncthreads();

    const unsigned pmask = 0xFFFFFFFFu << (8 * (pass + 1));
    const int shift = 8 * pass;
    const int stride = gridDim.x * blockDim.x;
    for (int i = blockIdx.x * blockDim.x + threadIdx.x; i < n; i += stride) {
        unsigned k = keys[i];
        if ((k & pmask) == prefix) atomicAdd(&h[(k >> shift) & 0xFFu], 1u);
    }
    __syncthreads();
    for (int i = threadIdx.x; i < 256; i += 256)
        if (h[i]) atomicAdd(&c->hist[pass][i], h[i]);
}

__global__ void __launch_bounds__(256)
reduceF_kernel(const unsigned* __restrict__ keys, const int* __restrict__ label,
               const float* __restrict__ nll, Ctrl* __restrict__ c,
               const int* __restrict__ factor_p, int n) {
    unsigned prefix24, rank; bool use_thr;
    select_chain(c, n, factor_p[0], 1, prefix24, rank, use_thr);  // bytes 3..1

    double local = 0.0;
    int cntl = 0;
    const int stride = gridDim.x * blockDim.x;
    for (int i = blockIdx.x * blockDim.x + threadIdx.x; i < n; i += stride) {
        int lab = label[i];
        float nl = nll[i];
        if (use_thr) {
            unsigned k = keys[i];
            unsigned top24 = k & 0xFFFFFF00u;
            bool is_pos = (lab != 0);
            if (is_pos || top24 < prefix24) {
                local += (double)nl; cntl++;
            } else if (top24 == prefix24) {
                // rare equal-set: resolve byte 0 later
                unsigned b = k & 0xFFu;
                atomicAdd(&c->bcnt[b], 1u);
                atomicAdd(&c->bsum[b], nl);
            }
        } else {
            if (lab != -1) { local += (double)nl; cntl++; }
        }
    }
#pragma unroll
    for (int off = 32; off > 0; off >>= 1) {
        local += __shfl_down(local, off);
        cntl  += __shfl_down(cntl, off);
    }
    __shared__ double sd[4];
    __shared__ int    si[4];
    int wid = threadIdx.x >> 6;
    if ((threadIdx.x & 63) == 0) { sd[wid] = local; si[wid] = cntl; }
    __syncthreads();
    if (threadIdx.x == 0) {
        atomicAdd(&c->sum, sd[0] + sd[1] + sd[2] + sd[3]);
        atomicAdd(&c->cnt, (unsigned)(si[0] + si[1] + si[2] + si[3]));
    }
}

__global__ void __launch_bounds__(256)
final_kernel(Ctrl* __restrict__ c, const int* __restrict__ factor_p,
             float* __restrict__ out, int n) {
    unsigned prefix, rank; bool use_thr;
    select_chain(c, n, factor_p[0], 1, prefix, rank, use_thr);

    __shared__ unsigned us[256];
    __shared__ float    fs[256];
    __shared__ double   ssum;
    __shared__ unsigned scnt;
    const int t = threadIdx.x;
    if (t == 0) { ssum = 0.0; scnt = 0u; }
    __syncthreads();

    if (use_thr) {
        unsigned bc = c->bcnt[t];
        float    bs = c->bsum[t];
        us[t] = bc; fs[t] = bs;
        __syncthreads();
#pragma unroll
        for (int off = 1; off < 256; off <<= 1) {
            unsigned uv = (t >= off) ? us[t - off] : 0u;
            float    fv = (t >= off) ? fs[t - off] : 0.f;
            __syncthreads();
            us[t] += uv; fs[t] += fv;
            __syncthreads();
        }
        unsigned incl = us[t], excl = incl - bc;
        if (bc > 0u && excl <= rank && rank < incl) {
            ssum = (double)fs[t];   // sum of nll over buckets <= selected byte0
            scnt = incl;            // count over buckets <= selected byte0
        }
        __syncthreads();
    }
    if (t == 0) {
        double s = c->sum + ssum;
        unsigned ctn = c->cnt + scnt;
        double denom = (ctn == 0u) ? 1.0 : (double)ctn;
        out[0] = (float)(s / denom);
    }
}

extern "C" void kernel_launch(void* const* d_in, const int* in_sizes, int n_in,
                              void* d_out, int out_size, void* d_ws, size_t ws_size,
                              hipStream_t stream) {
    const float* pred = (const float*)d_in[0];
    const int* label  = (const int*)d_in[1];
    const int* factor = (const int*)d_in[2];
    int n = in_sizes[1];
    float* out = (float*)d_out;

    char* ws = (char*)d_ws;
    Ctrl* c = (Ctrl*)ws;
    unsigned* keys = (unsigned*)(ws + 8192);
    float* nll = (float*)(ws + 8192 + (size_t)n * sizeof(unsigned));

    init_kernel<<<2, 256, 0, stream>>>((unsigned*)c, (int)(sizeof(Ctrl) / 4));
    row_kernel<<<2048, 256, 0, stream>>>((const f4*)pred, label, keys, nll, c, n);
    hist_kernel<<<1024, 256, 0, stream>>>(keys, c, factor, n, 2);
    hist_kernel<<<1024, 256, 0, stream>>>(keys, c, factor, n, 1);
    reduceF_kernel<<<2048, 256, 0, stream>>>(keys, label, nll, c, factor, n);
    final_kernel<<<1, 256, 0, stream>>>(c, factor, out, n);
}

// Round 4
// 139.702 us; speedup vs baseline: 1.5445x; 1.5445x over previous
//
#include <hip/hip_runtime.h>

// OHEM loss: exact k-th order statistic via radix select on a monotonic key,
// fused log-softmax NLL, masked mean.
//
// 6 launches:
//   init    : zero Ctrl
//   row     : pred (256MB) staged through LDS in 256-row tiles (coalesced
//             4KB/instr global loads; padded LDS, conflict-free b128 r/w)
//             -> keys, nll, hist[3] (top byte), pos_num
//   hist2/1 : redundant select-chain (LDS scan of completed hists) + filtered
//             histogram of the next byte
//   reduceF : select-chain to byte-1 level; definite rows -> reg sum/cnt;
//             equal-top24 rows (rare) -> 256 global buckets (hist0 fused)
//   final   : select byte 0 from buckets, combine, divide

typedef float f4 __attribute__((ext_vector_type(4)));

#define TILE_ROWS 256
#define ROW_F4    9   // 8 data f4 + 1 pad f4 -> conflict-free LDS b128 r/w

struct Ctrl {
    unsigned hist[4][256];   // hist[3..1] used
    unsigned pos_num;
    unsigned cnt;
    unsigned bcnt[256];      // byte-0 counts within selected 24-bit prefix
    float    bsum[256];      // nll sums per byte-0 bucket
    double   sum;
};

__global__ void init_kernel(unsigned* c, int words) {
    for (int i = threadIdx.x + blockIdx.x * blockDim.x; i < words;
         i += blockDim.x * gridDim.x)
        c[i] = 0u;
}

// Wave-aggregated LDS histogram add (top byte has few distinct values).
__device__ inline void wave_hist_add(unsigned* h, unsigned bucket) {
    unsigned long long todo = __ballot(1);
    while (todo) {
        int leader = (int)__builtin_ctzll(todo);
        unsigned b = __shfl(bucket, leader);
        unsigned long long same = __ballot(bucket == b) & todo;
        if ((int)(threadIdx.x & 63) == leader)
            atomicAdd(&h[b], (unsigned)__popcll(same));
        todo &= ~same;
    }
}

__global__ void __launch_bounds__(256)
row_kernel(const f4* __restrict__ pred4, const int* __restrict__ label,
           unsigned* __restrict__ keys, float* __restrict__ nll,
           Ctrl* __restrict__ c, int n) {
    __shared__ f4 tile[TILE_ROWS * ROW_F4];   // 36 KB
    __shared__ unsigned h[256];
    for (int i = threadIdx.x; i < 256; i += 256) h[i] = 0u;
    __syncthreads();

    const int tid = threadIdx.x;
    int pos_local = 0;
    const int tile_stride = gridDim.x * TILE_ROWS;

    for (int tbase = blockIdx.x * TILE_ROWS; tbase < n; tbase += tile_stride) {
        // ---- stage 256 rows x 128B, fully coalesced (4KB per instruction)
#pragma unroll
        for (int k = 0; k < 8; ++k) {
            int idx = (k << 8) + tid;                 // 0..2047
            f4 v = pred4[(size_t)tbase * 8 + idx];
            tile[(idx >> 3) * ROW_F4 + (idx & 7)] = v;
        }
        __syncthreads();

        // ---- compute: one thread per row
        int row = tbase + tid;
        float r[32];
#pragma unroll
        for (int j = 0; j < 8; ++j) {
            f4 v = tile[tid * ROW_F4 + j];
            r[4 * j + 0] = v.x; r[4 * j + 1] = v.y;
            r[4 * j + 2] = v.z; r[4 * j + 3] = v.w;
        }
        float m_nb = r[1];
#pragma unroll
        for (int j = 2; j < 32; ++j) m_nb = fmaxf(m_nb, r[j]);
        float m_all = fmaxf(m_nb, r[0]);

        float s = 0.f;
#pragma unroll
        for (int j = 0; j < 32; ++j) s += __expf(r[j] - m_all);

        int lab = label[row];
        int sl = lab; sl = sl < 0 ? 0 : sl; sl = sl > 31 ? 31 : sl;
        float xl = r[0];
#pragma unroll
        for (int j = 1; j < 32; ++j) xl = (j == sl) ? r[j] : xl;

        nll[row] = (m_all + __logf(s)) - xl;

        bool is_pos = (lab != 0);
        pos_local += is_pos ? 1 : 0;

        float ns = is_pos ? -__builtin_inff() : m_nb;
        unsigned u    = __float_as_uint(ns);
        unsigned ukey = (u & 0x80000000u) ? ~u : (u | 0x80000000u);
        unsigned dkey = ~ukey;                 // ascending dkey = descending float
        keys[row] = dkey;
        wave_hist_add(h, dkey >> 24);

        __syncthreads();   // protect tile before next stage
    }

#pragma unroll
    for (int off = 32; off > 0; off >>= 1) pos_local += __shfl_down(pos_local, off);
    __shared__ int wsum[4];
    int wid = threadIdx.x >> 6;
    if ((threadIdx.x & 63) == 0) wsum[wid] = pos_local;
    __syncthreads();
    if (threadIdx.x == 0)
        atomicAdd(&c->pos_num, (unsigned)(wsum[0] + wsum[1] + wsum[2] + wsum[3]));

    for (int i = threadIdx.x; i < 256; i += 256)
        if (h[i]) atomicAdd(&c->hist[3][i], h[i]);
}

// Block-redundant radix select over completed histograms 3..upto_pass.
// Requires blockDim.x == 256.
__device__ void select_chain(const Ctrl* __restrict__ c, int n, int factor,
                             int upto_pass, unsigned& prefix_out,
                             unsigned& rank_out, bool& use_thr_out) {
    __shared__ unsigned s[256];
    __shared__ unsigned sh_byte, sh_rank;
    const int t = threadIdx.x;

    long long pos     = (long long)c->pos_num;
    long long neg_sum = pos * (long long)factor;
    long long num_neg = (long long)n - pos;
    long long idx     = neg_sum - 1;
    if (idx < 0) idx = 0;
    if (idx > (long long)n - 1) idx = (long long)n - 1;
    unsigned rank   = (unsigned)idx;
    unsigned prefix = 0u;

    for (int p = 3; p >= upto_pass; --p) {
        unsigned cnt = c->hist[p][t];
        __syncthreads();
        s[t] = cnt;
        __syncthreads();
#pragma unroll
        for (int off = 1; off < 256; off <<= 1) {
            unsigned v = (t >= off) ? s[t - off] : 0u;
            __syncthreads();
            s[t] += v;
            __syncthreads();
        }
        unsigned incl = s[t], excl = incl - cnt;
        if (cnt > 0u && excl <= rank && rank < incl) {
            sh_byte = (unsigned)t;
            sh_rank = rank - excl;
        }
        __syncthreads();
        prefix |= sh_byte << (8 * p);
        rank = sh_rank;
        __syncthreads();
    }
    prefix_out  = prefix;
    rank_out    = rank;
    use_thr_out = (num_neg > neg_sum);
}

__global__ void __launch_bounds__(256)
hist_kernel(const unsigned* __restrict__ keys, Ctrl* __restrict__ c,
            const int* __restrict__ factor_p, int n, int pass) {
    unsigned prefix, rank; bool use_thr;
    select_chain(c, n, factor_p[0], pass + 1, prefix, rank, use_thr);

    __shared__ unsigned h[256];
    for (int i = threadIdx.x; i < 256; i += 256) h[i] = 0u;
    __syncthreads();

    const unsigned pmask = 0xFFFFFFFFu << (8 * (pass + 1));
    const int shift = 8 * pass;
    const int stride = gridDim.x * blockDim.x;
    for (int i = blockIdx.x * blockDim.x + threadIdx.x; i < n; i += stride) {
        unsigned k = keys[i];
        if ((k & pmask) == prefix) atomicAdd(&h[(k >> shift) & 0xFFu], 1u);
    }
    __syncthreads();
    for (int i = threadIdx.x; i < 256; i += 256)
        if (h[i]) atomicAdd(&c->hist[pass][i], h[i]);
}

__global__ void __launch_bounds__(256)
reduceF_kernel(const unsigned* __restrict__ keys, const int* __restrict__ label,
               const float* __restrict__ nll, Ctrl* __restrict__ c,
               const int* __restrict__ factor_p, int n) {
    unsigned prefix24, rank; bool use_thr;
    select_chain(c, n, factor_p[0], 1, prefix24, rank, use_thr);  // bytes 3..1

    double local = 0.0;
    int cntl = 0;
    const int stride = gridDim.x * blockDim.x;
    for (int i = blockIdx.x * blockDim.x + threadIdx.x; i < n; i += stride) {
        int lab = label[i];
        float nl = nll[i];
        if (use_thr) {
            unsigned k = keys[i];
            unsigned top24 = k & 0xFFFFFF00u;
            bool is_pos = (lab != 0);
            if (is_pos || top24 < prefix24) {
                local += (double)nl; cntl++;
            } else if (top24 == prefix24) {
                unsigned b = k & 0xFFu;
                atomicAdd(&c->bcnt[b], 1u);
                atomicAdd(&c->bsum[b], nl);
            }
        } else {
            if (lab != -1) { local += (double)nl; cntl++; }
        }
    }
#pragma unroll
    for (int off = 32; off > 0; off >>= 1) {
        local += __shfl_down(local, off);
        cntl  += __shfl_down(cntl, off);
    }
    __shared__ double sd[4];
    __shared__ int    si[4];
    int wid = threadIdx.x >> 6;
    if ((threadIdx.x & 63) == 0) { sd[wid] = local; si[wid] = cntl; }
    __syncthreads();
    if (threadIdx.x == 0) {
        atomicAdd(&c->sum, sd[0] + sd[1] + sd[2] + sd[3]);
        atomicAdd(&c->cnt, (unsigned)(si[0] + si[1] + si[2] + si[3]));
    }
}

__global__ void __launch_bounds__(256)
final_kernel(Ctrl* __restrict__ c, const int* __restrict__ factor_p,
             float* __restrict__ out, int n) {
    unsigned prefix, rank; bool use_thr;
    select_chain(c, n, factor_p[0], 1, prefix, rank, use_thr);

    __shared__ unsigned us[256];
    __shared__ float    fs[256];
    __shared__ double   ssum;
    __shared__ unsigned scnt;
    const int t = threadIdx.x;
    if (t == 0) { ssum = 0.0; scnt = 0u; }
    __syncthreads();

    if (use_thr) {
        unsigned bc = c->bcnt[t];
        float    bs = c->bsum[t];
        us[t] = bc; fs[t] = bs;
        __syncthreads();
#pragma unroll
        for (int off = 1; off < 256; off <<= 1) {
            unsigned uv = (t >= off) ? us[t - off] : 0u;
            float    fv = (t >= off) ? fs[t - off] : 0.f;
            __syncthreads();
            us[t] += uv; fs[t] += fv;
            __syncthreads();
        }
        unsigned incl = us[t], excl = incl - bc;
        if (bc > 0u && excl <= rank && rank < incl) {
            ssum = (double)fs[t];   // nll sum over equal-set rows with byte0 <= sel
            scnt = incl;            // their count
        }
        __syncthreads();
    }
    if (t == 0) {
        double s = c->sum + ssum;
        unsigned ctn = c->cnt + scnt;
        double denom = (ctn == 0u) ? 1.0 : (double)ctn;
        out[0] = (float)(s / denom);
    }
}

extern "C" void kernel_launch(void* const* d_in, const int* in_sizes, int n_in,
                              void* d_out, int out_size, void* d_ws, size_t ws_size,
                              hipStream_t stream) {
    const float* pred = (const float*)d_in[0];
    const int* label  = (const int*)d_in[1];
    const int* factor = (const int*)d_in[2];
    int n = in_sizes[1];
    float* out = (float*)d_out;

    char* ws = (char*)d_ws;
    Ctrl* c = (Ctrl*)ws;
    unsigned* keys = (unsigned*)(ws + 8192);
    float* nll = (float*)(ws + 8192 + (size_t)n * sizeof(unsigned));

    init_kernel<<<2, 256, 0, stream>>>((unsigned*)c, (int)(sizeof(Ctrl) / 4));
    row_kernel<<<2048, 256, 0, stream>>>((const f4*)pred, label, keys, nll, c, n);
    hist_kernel<<<1024, 256, 0, stream>>>(keys, c, factor, n, 2);
    hist_kernel<<<1024, 256, 0, stream>>>(keys, c, factor, n, 1);
    reduceF_kernel<<<2048, 256, 0, stream>>>(keys, label, nll, c, factor, n);
    final_kernel<<<1, 256, 0, stream>>>(c, factor, out, n);
}